// Round 3
// baseline (501.452 us; speedup 1.0000x reference)
//
#include <hip/hip_runtime.h>

typedef __bf16 bf16x8 __attribute__((ext_vector_type(8)));
typedef float f32x4 __attribute__((ext_vector_type(4)));

#define HW 16384
#define QKV_C 1152
#define SPV 66   // V^T buffer stride: scalar col-writes spread banks (<=2-way)
#define SPB 72   // [tok][c] buffer stride: b128 frag reads + uint4 staging conflict-free

union U4B8 { uint4 u; bf16x8 v; __bf16 h[8]; };
union U2B4 { uint2 u; __bf16 h[4]; };

// ---------------------------------------------------------------------------
// K0: xT[b][hw][c] (bf16) = transpose(x[b][c][hw]) — done ONCE (was 9x inside
// k_qkv). Gather-8-c per lane -> b128 LDS write (conflict-free), coalesced out.
// ---------------------------------------------------------------------------
__global__ __launch_bounds__(256) void k_tr(const float* __restrict__ x,
    __bf16* __restrict__ xT)
{
    __shared__ __bf16 T[64 * 72];
    const int tid = threadIdx.x;
    const int hw0 = blockIdx.x * 64;
    const int c0  = blockIdx.y * 64;
    const int b   = blockIdx.z;
    const float* xb = x + ((size_t)b * 384 + c0) * HW + hw0;
#pragma unroll
    for (int ph = 0; ph < 2; ++ph) {
        int unit = ph * 256 + tid;
        int hw = unit & 63, c8 = unit >> 6;          // c8 in 0..7
        const float* xp = xb + (size_t)(c8 * 8) * HW + hw;
        U4B8 t;
#pragma unroll
        for (int j = 0; j < 8; ++j) t.h[j] = (__bf16)xp[(size_t)j * HW];
        *(uint4*)(T + hw * 72 + c8 * 8) = t.u;
    }
    __syncthreads();
    __bf16* ob = xT + ((size_t)b * HW + hw0) * 384 + c0;
#pragma unroll
    for (int ph = 0; ph < 2; ++ph) {
        int unit = ph * 256 + tid;
        int hw = unit >> 3, c8 = unit & 7;
        *(uint4*)(ob + (size_t)hw * 384 + c8 * 8) = *(const uint4*)(T + hw * 72 + c8 * 8);
    }
}

// ---------------------------------------------------------------------------
// K1: qkv[b][hw][o] (bf16) = w_qkv[o][c] * xT[b][hw][c]^T + b_qkv[o]
// Both operands k-contiguous now: pure b128 staging, no transpose, no scalar
// gathers in the hot loop.
// ---------------------------------------------------------------------------
__global__ __launch_bounds__(256) void k_qkv(const __bf16* __restrict__ xT,
    const float* __restrict__ wq, const float* __restrict__ bq,
    __bf16* __restrict__ qkv)
{
    __shared__ __bf16 As[128 * 72];  // w_qkv tile [o][c]
    __shared__ __bf16 Bs[128 * 72];  // xT tile [hw][c]
    const int tid = threadIdx.x;
    const int hw0 = blockIdx.x * 128;
    const int o0  = blockIdx.y * 128;
    const int b   = blockIdx.z;
    const __bf16* xb = xT + (size_t)b * HW * 384;

    f32x4 acc[4][4];
#pragma unroll
    for (int i = 0; i < 4; ++i)
#pragma unroll
        for (int j = 0; j < 4; ++j)
#pragma unroll
            for (int e = 0; e < 4; ++e) acc[i][j][e] = 0.0f;

    const int l = tid & 63;
    const int wv = tid >> 6;
    const int wm = wv & 1;    // o 64-half
    const int wn = wv >> 1;   // hw 64-half
    const int l16 = l & 15, quad = l >> 4;

    for (int kt = 0; kt < 6; ++kt) {
        const int c0 = kt * 64;
        // stage w_qkv tile: gather 8 consecutive c (2 float4), uint4 write (free)
#pragma unroll
        for (int it = 0; it < 4; ++it) {
            int unit = it * 256 + tid;
            int o = unit >> 3, c8 = unit & 7;
            const float* wp = wq + (size_t)(o0 + o) * 384 + c0 + c8 * 8;
            float4 f0 = *(const float4*)(wp);
            float4 f1 = *(const float4*)(wp + 4);
            U4B8 t;
            t.h[0] = (__bf16)f0.x; t.h[1] = (__bf16)f0.y;
            t.h[2] = (__bf16)f0.z; t.h[3] = (__bf16)f0.w;
            t.h[4] = (__bf16)f1.x; t.h[5] = (__bf16)f1.y;
            t.h[6] = (__bf16)f1.z; t.h[7] = (__bf16)f1.w;
            *(uint4*)(As + o * 72 + c8 * 8) = t.u;
        }
        // stage xT tile: uint4 loads (8 rows x 128B per instr), uint4 writes (free)
#pragma unroll
        for (int it = 0; it < 4; ++it) {
            int unit = it * 256 + tid;
            int hw = unit >> 3, c8 = unit & 7;
            *(uint4*)(Bs + hw * 72 + c8 * 8) =
                *(const uint4*)(xb + (size_t)(hw0 + hw) * 384 + c0 + c8 * 8);
        }
        __syncthreads();
#pragma unroll
        for (int ks = 0; ks < 2; ++ks) {
            bf16x8 a[4], bb[4];
#pragma unroll
            for (int t = 0; t < 4; ++t)
                a[t] = *(const bf16x8*)(As + (wm * 64 + t * 16 + l16) * 72 + ks * 32 + quad * 8);
#pragma unroll
            for (int t = 0; t < 4; ++t)
                bb[t] = *(const bf16x8*)(Bs + (wn * 64 + t * 16 + l16) * 72 + ks * 32 + quad * 8);
#pragma unroll
            for (int mt = 0; mt < 4; ++mt)
#pragma unroll
                for (int nt = 0; nt < 4; ++nt)
                    acc[mt][nt] = __builtin_amdgcn_mfma_f32_16x16x32_bf16(
                        a[mt], bb[nt], acc[mt][nt], 0, 0, 0);
        }
        __syncthreads();
    }

    // epilogue: D[m=o][n=hw]; col=l16 -> hw, row=quad*4+e -> o
    __bf16* qb = qkv + (size_t)b * HW * QKV_C;
#pragma unroll
    for (int mt = 0; mt < 4; ++mt) {
        int oo = o0 + wm * 64 + mt * 16 + quad * 4;
        float4 bias = *(const float4*)(bq + oo);
#pragma unroll
        for (int nt = 0; nt < 4; ++nt) {
            int hw = hw0 + wn * 64 + nt * 16 + l16;
            U2B4 t;
            t.h[0] = (__bf16)(acc[mt][nt][0] + bias.x);
            t.h[1] = (__bf16)(acc[mt][nt][1] + bias.y);
            t.h[2] = (__bf16)(acc[mt][nt][2] + bias.z);
            t.h[3] = (__bf16)(acc[mt][nt][3] + bias.w);
            *(uint2*)(qb + (size_t)hw * QKV_C + oo) = t.u;
        }
    }
}

// ---------------------------------------------------------------------------
// K2: windowed MHA. One wave per (window, head, branch). 192 thr = 3 waves.
// All global loads now coalesced (8 tokens x 128 B per instruction) via LDS
// staging; one reusable [tok][c] buffer (Q -> K -> P -> O) + V^T buffer.
// ---------------------------------------------------------------------------
__global__ __launch_bounds__(192) void k_attn(const __bf16* __restrict__ qkv,
    __bf16* __restrict__ y1, __bf16* __restrict__ y2)
{
    __shared__ __bf16 smV[3][64 * SPV];
    __shared__ __bf16 smB[3][64 * SPB];
    const int tid = threadIdx.x;
    const int l = tid & 63, wv = tid >> 6;
    const int wid = blockIdx.x * 3 + wv;
    const bool shifted = wid >= 6144;
    const int w2 = shifted ? wid - 6144 : wid;
    const int head = w2 % 6;
    const int win = w2 / 6;
    const int nw = shifted ? 17 : 16;
    const int wx = win % nw;
    const int t2 = win / nw;
    const int wy = t2 % nw;
    const int b  = t2 / nw;
    const int h0 = wy * 8 - (shifted ? 4 : 0);
    const int w0 = wx * 8 - (shifted ? 4 : 0);
    const __bf16* qb = qkv + (size_t)b * HW * QKV_C;
    __bf16* VT = smV[wv];
    __bf16* BB = smB[wv];
    const int l16 = l & 15, quad = l >> 4;
    const int cbase = head * 64;

    // staging address per lane: 8 tokens x 8 c8-chunks per pass
    const int stok = l >> 3, sc8 = l & 7;
    int soff[8];                       // byte-elem offset into qb, -1 = OOB
#pragma unroll
    for (int it = 0; it < 8; ++it) {
        int tok = it * 8 + stok;
        int hh = h0 + (tok >> 3), ww = w0 + (tok & 7);
        soff[it] = ((unsigned)hh < 128u && (unsigned)ww < 128u)
                 ? (hh * 128 + ww) * QKV_C + cbase + sc8 * 8 : -1;
    }

    // stage V^T [c][tok]
#pragma unroll
    for (int it = 0; it < 8; ++it) {
        int tok = it * 8 + stok;
        U4B8 t;
        if (soff[it] >= 0) t.u = *(const uint4*)(qb + soff[it] + 768);
        else t.u = make_uint4(0, 0, 0, 0);
#pragma unroll
        for (int e = 0; e < 8; ++e) VT[(sc8 * 8 + e) * SPV + tok] = t.h[e];
    }
    // stage Q [tok][c]
#pragma unroll
    for (int it = 0; it < 8; ++it) {
        int tok = it * 8 + stok;
        U4B8 t;
        if (soff[it] >= 0) t.u = *(const uint4*)(qb + soff[it]);
        else t.u = make_uint4(0, 0, 0, 0);
        *(uint4*)(BB + tok * SPB + sc8 * 8) = t.u;
    }
    __syncthreads();
    bf16x8 aq[2][4];
#pragma unroll
    for (int ks = 0; ks < 2; ++ks)
#pragma unroll
        for (int t = 0; t < 4; ++t)
            aq[ks][t] = *(const bf16x8*)(BB + (t * 16 + l16) * SPB + ks * 32 + quad * 8);
    __syncthreads();
    // stage K [tok][c] (overwrites Q region; Q frags live in regs)
#pragma unroll
    for (int it = 0; it < 8; ++it) {
        int tok = it * 8 + stok;
        U4B8 t;
        if (soff[it] >= 0) t.u = *(const uint4*)(qb + soff[it] + 384);
        else t.u = make_uint4(0, 0, 0, 0);
        *(uint4*)(BB + tok * SPB + sc8 * 8) = t.u;
    }
    __syncthreads();

    // S = Q K^T
    f32x4 s[4][4];
#pragma unroll
    for (int i = 0; i < 4; ++i)
#pragma unroll
        for (int j = 0; j < 4; ++j)
#pragma unroll
            for (int e = 0; e < 4; ++e) s[i][j][e] = 0.0f;
#pragma unroll
    for (int ks = 0; ks < 2; ++ks) {
        bf16x8 bk[4];
#pragma unroll
        for (int t = 0; t < 4; ++t)
            bk[t] = *(const bf16x8*)(BB + (t * 16 + l16) * SPB + ks * 32 + quad * 8);
#pragma unroll
        for (int mt = 0; mt < 4; ++mt)
#pragma unroll
            for (int nt = 0; nt < 4; ++nt)
                s[mt][nt] = __builtin_amdgcn_mfma_f32_16x16x32_bf16(
                    aq[ks][mt], bk[nt], s[mt][nt], 0, 0, 0);
    }

    // softmax (scale 1/8); row = mt*16 + quad*4 + e, cols across l16 x nt
    float pr[4][4][4];
#pragma unroll
    for (int mt = 0; mt < 4; ++mt) {
#pragma unroll
        for (int e = 0; e < 4; ++e) {
            float m_ = fmaxf(fmaxf(s[mt][0][e], s[mt][1][e]),
                             fmaxf(s[mt][2][e], s[mt][3][e]));
#pragma unroll
            for (int st = 1; st < 16; st <<= 1) m_ = fmaxf(m_, __shfl_xor(m_, st, 64));
            float p[4];
#pragma unroll
            for (int nt = 0; nt < 4; ++nt) p[nt] = __expf((s[mt][nt][e] - m_) * 0.125f);
            float sum = p[0] + p[1] + p[2] + p[3];
#pragma unroll
            for (int st = 1; st < 16; st <<= 1) sum += __shfl_xor(sum, st, 64);
            float r = __fdividef(1.0f, sum);
#pragma unroll
            for (int nt = 0; nt < 4; ++nt) pr[mt][nt][e] = p[nt] * r;
        }
    }
    __syncthreads();   // bk reads retired before P overwrites BB
#pragma unroll
    for (int mt = 0; mt < 4; ++mt)
#pragma unroll
        for (int e = 0; e < 4; ++e) {
            int row = mt * 16 + quad * 4 + e;
#pragma unroll
            for (int nt = 0; nt < 4; ++nt)
                BB[row * SPB + nt * 16 + l16] = (__bf16)pr[mt][nt][e];
        }
    __syncthreads();

    // O = P V
    f32x4 o[4][4];
#pragma unroll
    for (int i = 0; i < 4; ++i)
#pragma unroll
        for (int j = 0; j < 4; ++j)
#pragma unroll
            for (int e = 0; e < 4; ++e) o[i][j][e] = 0.0f;
#pragma unroll
    for (int ks = 0; ks < 2; ++ks) {
        bf16x8 ap[4], bvv[4];
#pragma unroll
        for (int t = 0; t < 4; ++t)
            ap[t] = *(const bf16x8*)(BB + (t * 16 + l16) * SPB + ks * 32 + quad * 8);
#pragma unroll
        for (int t = 0; t < 4; ++t)
            bvv[t] = *(const bf16x8*)(VT + (t * 16 + l16) * SPV + ks * 32 + quad * 8);
#pragma unroll
        for (int mt = 0; mt < 4; ++mt)
#pragma unroll
            for (int nt = 0; nt < 4; ++nt)
                o[mt][nt] = __builtin_amdgcn_mfma_f32_16x16x32_bf16(
                    ap[mt], bvv[nt], o[mt][nt], 0, 0, 0);
    }
    __syncthreads();   // ap reads retired before O overwrites BB

    // O -> BB as [tok][c]
#pragma unroll
    for (int mt = 0; mt < 4; ++mt)
#pragma unroll
        for (int e = 0; e < 4; ++e) {
            int row = mt * 16 + quad * 4 + e;
#pragma unroll
            for (int nt = 0; nt < 4; ++nt)
                BB[row * SPB + nt * 16 + l16] = (__bf16)o[mt][nt][e];
        }
    __syncthreads();

    __bf16* yb = (shifted ? y2 : y1) + (size_t)b * HW * 384;
#pragma unroll
    for (int it = 0; it < 8; ++it) {
        int tok = it * 8 + stok;
        if (soff[it] >= 0) {
            int hh = h0 + (tok >> 3), ww = w0 + (tok & 7);
            *(uint4*)(yb + (size_t)(hh * 128 + ww) * 384 + cbase + sc8 * 8) =
                *(const uint4*)(BB + tok * SPB + sc8 * 8);
        }
    }
}

// ---------------------------------------------------------------------------
// K3: out[b][o][hw] (fp32) = w_head[o][c] * (y1+y2)[b][hw][c] + b_head[o]
// ---------------------------------------------------------------------------
__global__ __launch_bounds__(256) void k_head(const __bf16* __restrict__ y1,
    const __bf16* __restrict__ y2, const float* __restrict__ wh,
    const float* __restrict__ bh, float* __restrict__ out)
{
    __shared__ __bf16 As[128 * 72];  // (y1+y2) tile [hw][c]
    __shared__ __bf16 Bs[128 * 72];  // w_head tile [o][c]
    const int tid = threadIdx.x;
    const int hw0 = blockIdx.x * 128;
    const int o0  = blockIdx.y * 128;
    const int b   = blockIdx.z;
    const __bf16* y1b = y1 + (size_t)b * HW * 384;
    const __bf16* y2b = y2 + (size_t)b * HW * 384;

    f32x4 acc[4][4];
#pragma unroll
    for (int i = 0; i < 4; ++i)
#pragma unroll
        for (int j = 0; j < 4; ++j)
#pragma unroll
            for (int e = 0; e < 4; ++e) acc[i][j][e] = 0.0f;

    const int l = tid & 63, wv = tid >> 6;
    const int wm = wv & 1;    // hw 64-half
    const int wn = wv >> 1;   // o 64-half
    const int l16 = l & 15, quad = l >> 4;

    for (int kt = 0; kt < 6; ++kt) {
        const int c0 = kt * 64;
        // stage y tile (fused y1+y2)
#pragma unroll
        for (int it = 0; it < 4; ++it) {
            int unit = it * 256 + tid;
            int hw = unit >> 3, c8 = unit & 7;
            size_t off = (size_t)(hw0 + hw) * 384 + c0 + c8 * 8;
            U4B8 t1, t2, r;
            t1.u = *(const uint4*)(y1b + off);
            t2.u = *(const uint4*)(y2b + off);
#pragma unroll
            for (int e = 0; e < 8; ++e)
                r.h[e] = (__bf16)((float)t1.h[e] + (float)t2.h[e]);
            *(uint4*)(As + hw * 72 + c8 * 8) = r.u;
        }
        // stage w_head tile: gather-8, uint4 write (conflict-free)
#pragma unroll
        for (int it = 0; it < 4; ++it) {
            int unit = it * 256 + tid;
            int o = unit >> 3, c8 = unit & 7;
            const float* wp = wh + (size_t)(o0 + o) * 384 + c0 + c8 * 8;
            float4 f0 = *(const float4*)(wp);
            float4 f1 = *(const float4*)(wp + 4);
            U4B8 t;
            t.h[0] = (__bf16)f0.x; t.h[1] = (__bf16)f0.y;
            t.h[2] = (__bf16)f0.z; t.h[3] = (__bf16)f0.w;
            t.h[4] = (__bf16)f1.x; t.h[5] = (__bf16)f1.y;
            t.h[6] = (__bf16)f1.z; t.h[7] = (__bf16)f1.w;
            *(uint4*)(Bs + o * 72 + c8 * 8) = t.u;
        }
        __syncthreads();
#pragma unroll
        for (int ks = 0; ks < 2; ++ks) {
            bf16x8 a[4], bb[4];
#pragma unroll
            for (int t = 0; t < 4; ++t)
                a[t] = *(const bf16x8*)(As + (wm * 64 + t * 16 + l16) * 72 + ks * 32 + quad * 8);
#pragma unroll
            for (int t = 0; t < 4; ++t)
                bb[t] = *(const bf16x8*)(Bs + (wn * 64 + t * 16 + l16) * 72 + ks * 32 + quad * 8);
#pragma unroll
            for (int mt = 0; mt < 4; ++mt)
#pragma unroll
                for (int nt = 0; nt < 4; ++nt)
                    acc[mt][nt] = __builtin_amdgcn_mfma_f32_16x16x32_bf16(
                        a[mt], bb[nt], acc[mt][nt], 0, 0, 0);
        }
        __syncthreads();
    }

    // epilogue: D[m=hw][n=o]; col=l16 -> o, rows quad*4+e -> hw (float4 stores)
#pragma unroll
    for (int nt = 0; nt < 4; ++nt) {
        int oo = o0 + wn * 64 + nt * 16 + l16;
        float bb_ = bh[oo];
        float* ob = out + ((size_t)b * 384 + oo) * HW + hw0 + wm * 64;
#pragma unroll
        for (int mt = 0; mt < 4; ++mt) {
            float4 f;
            f.x = acc[mt][nt][0] + bb_;
            f.y = acc[mt][nt][1] + bb_;
            f.z = acc[mt][nt][2] + bb_;
            f.w = acc[mt][nt][3] + bb_;
            *(float4*)(ob + mt * 16 + quad * 4) = f;
        }
    }
}

extern "C" void kernel_launch(void* const* d_in, const int* in_sizes, int n_in,
                              void* d_out, int out_size, void* d_ws, size_t ws_size,
                              hipStream_t stream) {
    const float* x  = (const float*)d_in[0];
    const float* wq = (const float*)d_in[1];
    const float* bq = (const float*)d_in[2];
    const float* wh = (const float*)d_in[3];
    const float* bh = (const float*)d_in[4];
    float* out = (float*)d_out;

    __bf16* qkv = (__bf16*)d_ws;                       // 151 MB
    __bf16* y1  = qkv + (size_t)4 * HW * QKV_C;        // 50 MB
    __bf16* y2  = y1 + (size_t)4 * HW * 384;           // 50 MB
    __bf16* xT  = y2;  // alias: xT dead before k_attn writes y2 (stream-ordered)

    k_tr  <<<dim3(256, 6, 4), 256, 0, stream>>>(x, xT);
    k_qkv <<<dim3(128, 9, 4), 256, 0, stream>>>(xT, wq, bq, qkv);
    k_attn<<<dim3(4360), 192, 0, stream>>>(qkv, y1, y2);
    k_head<<<dim3(128, 3, 4), 256, 0, stream>>>(y1, y2, wh, bh, out);
}